// Round 1
// baseline (5614.301 us; speedup 1.0000x reference)
//
#include <hip/hip_runtime.h>
#include <hip/hip_bf16.h>

// GCN: 2x GCNConv(128->128) + LeakyReLU(0.1) + mean over channels.
// N=50000 nodes, E=1600000 edges, D=128. All fp32.
//
// Pipeline:
//   1. deg count (u32 atomics over dst) -> dinv = rsqrt(deg+1)   [self-loop +1]
//   2. h1 = x @ W1                       (LDS-tiled fp32 GEMM)
//   3. agg1 = selfloop_init(h1) + edge_scatter(h1)   (f32 atomics)
//   4. h2 = leakyrelu(agg1 + b1) @ W2    (transform fused into A staging)
//   5. agg2 = selfloop_init(h2) + edge_scatter(h2)
//   6. out[v] = mean_c(agg2[v][c] + b2[c])

#define N_NODES 50000
#define N_EDGES 1600000
#define D 128

// ---------------- degree ----------------
__global__ void count_deg_kernel(const int* __restrict__ dst, unsigned* __restrict__ cnt, int E) {
    int e = blockIdx.x * blockDim.x + threadIdx.x;
    if (e < E) atomicAdd(&cnt[dst[e]], 1u);
}

__global__ void dinv_kernel(float* __restrict__ buf, int N) {
    int i = blockIdx.x * blockDim.x + threadIdx.x;
    if (i < N) {
        unsigned c = ((const unsigned*)buf)[i];
        buf[i] = rsqrtf((float)(c + 1u));   // +1 self-loop; deg always >= 1
    }
}

// ---------------- GEMM: C[M,128] = act(A + bias) @ W[128,128] ----------------
#define TM 64
__global__ __launch_bounds__(256) void gemm_kernel(
    const float* __restrict__ A, const float* __restrict__ W,
    float* __restrict__ C, const float* __restrict__ bias, int act, int M) {
    __shared__ float Ws[128 * 128];   // 64 KB
    __shared__ float As[TM * 128];    // 32 KB
    int t = threadIdx.x;
    int row0 = blockIdx.x * TM;

    // stage W: 4096 float4 across 256 threads
    {
        const float4* Wv = (const float4*)W;
        float4* Wsv = (float4*)Ws;
#pragma unroll
        for (int i = 0; i < 16; i++) Wsv[t + i * 256] = Wv[t + i * 256];
    }
    // stage A tile (with optional +bias, leakyrelu fused)
    {
        float4* Asv = (float4*)As;
#pragma unroll
        for (int i = 0; i < (TM * 32) / 256; i++) {  // 8 float4 per thread
            int f = t + i * 256;
            int r = f >> 5;          // row in tile
            int c4 = f & 31;         // float4 col
            int row = row0 + r;
            float4 v = make_float4(0.f, 0.f, 0.f, 0.f);
            if (row < M) v = ((const float4*)(A + (long)row * D))[c4];
            if (act) {
                float4 b = ((const float4*)bias)[c4];
                v.x += b.x; v.y += b.y; v.z += b.z; v.w += b.w;
                v.x = v.x >= 0.f ? v.x : 0.1f * v.x;
                v.y = v.y >= 0.f ? v.y : 0.1f * v.y;
                v.z = v.z >= 0.f ? v.z : 0.1f * v.z;
                v.w = v.w >= 0.f ? v.w : 0.1f * v.w;
            }
            Asv[f] = v;
        }
    }
    __syncthreads();

    int tx = t & 31;   // cols tx*4 .. tx*4+3
    int ty = t >> 5;   // rows ty*8 .. ty*8+7
    float4 acc[8];
#pragma unroll
    for (int r = 0; r < 8; r++) acc[r] = make_float4(0.f, 0.f, 0.f, 0.f);

    const float4* Wsv = (const float4*)Ws;
    for (int k = 0; k < 128; k += 4) {
        float4 w0 = Wsv[(k + 0) * 32 + tx];
        float4 w1 = Wsv[(k + 1) * 32 + tx];
        float4 w2 = Wsv[(k + 2) * 32 + tx];
        float4 w3 = Wsv[(k + 3) * 32 + tx];
#pragma unroll
        for (int r = 0; r < 8; r++) {
            int row = ty * 8 + r;
            float4 a = *(const float4*)(As + row * 128 + k);
            acc[r].x += a.x * w0.x + a.y * w1.x + a.z * w2.x + a.w * w3.x;
            acc[r].y += a.x * w0.y + a.y * w1.y + a.z * w2.y + a.w * w3.y;
            acc[r].z += a.x * w0.z + a.y * w1.z + a.z * w2.z + a.w * w3.z;
            acc[r].w += a.x * w0.w + a.y * w1.w + a.z * w2.w + a.w * w3.w;
        }
    }
#pragma unroll
    for (int r = 0; r < 8; r++) {
        int row = row0 + ty * 8 + r;
        if (row < M) ((float4*)(C + (long)row * D))[tx] = acc[r];
    }
}

// ---------------- aggregate ----------------
// agg[v] = h[v] * dinv[v]^2   (self-loop term; also serves as the zero-init)
__global__ void selfloop_init_kernel(const float* __restrict__ h, const float* __restrict__ dinv,
                                     float* __restrict__ agg, int N) {
    long i = (long)blockIdx.x * blockDim.x + threadIdx.x;  // float4 index
    if (i >= (long)N * (D / 4)) return;
    int node = (int)(i >> 5);
    float w = dinv[node];
    w = w * w;
    float4 v = ((const float4*)h)[i];
    v.x *= w; v.y *= w; v.z *= w; v.w *= w;
    ((float4*)agg)[i] = v;
}

// 32 lanes per edge; each lane: float4 gather + 4 scalar f32 atomics
__global__ __launch_bounds__(256) void edge_scatter_kernel(
    const int* __restrict__ src, const int* __restrict__ dst,
    const float* __restrict__ dinv, const float* __restrict__ h,
    float* __restrict__ agg, int E) {
    int lane = threadIdx.x & 31;
    int slot = threadIdx.x >> 5;                 // 8 edges per block
    long e = (long)blockIdx.x * 8 + slot;
    if (e >= E) return;
    int s = src[e], d = dst[e];
    float w = dinv[s] * dinv[d];
    float4 v = ((const float4*)(h + (long)s * D))[lane];
    float* a = agg + (long)d * D + lane * 4;
    atomicAdd(a + 0, v.x * w);
    atomicAdd(a + 1, v.y * w);
    atomicAdd(a + 2, v.z * w);
    atomicAdd(a + 3, v.w * w);
}

// ---------------- mean ----------------
__global__ void mean_kernel(const float* __restrict__ agg, const float* __restrict__ b2,
                            float* __restrict__ out, int N) {
    int t = blockIdx.x * blockDim.x + threadIdx.x;
    int node = t >> 5;
    int lane = t & 31;
    if (node >= N) return;
    float4 v = ((const float4*)(agg + (long)node * D))[lane];
    float4 b = ((const float4*)b2)[lane];
    float s = (v.x + b.x) + (v.y + b.y) + (v.z + b.z) + (v.w + b.w);
#pragma unroll
    for (int off = 16; off > 0; off >>= 1) s += __shfl_down(s, off, 32);
    if (lane == 0) out[node] = s * (1.0f / 128.0f);
}

extern "C" void kernel_launch(void* const* d_in, const int* in_sizes, int n_in,
                              void* d_out, int out_size, void* d_ws, size_t ws_size,
                              hipStream_t stream) {
    const float* x  = (const float*)d_in[0];
    const int* ei   = (const int*)d_in[1];      // [2, E] flattened: src then dst
    const float* W1 = (const float*)d_in[2];
    const float* b1 = (const float*)d_in[3];
    const float* W2 = (const float*)d_in[4];
    const float* b2 = (const float*)d_in[5];
    float* out = (float*)d_out;

    const int N = N_NODES;
    const int E = in_sizes[1] / 2;
    const int* src = ei;
    const int* dst = ei + E;

    // workspace layout (floats): dinv [51200] | bufA [N*D] | bufB [N*D]
    float* dinv = (float*)d_ws;
    float* bufA = dinv + 51200;
    float* bufB = bufA + (long)N * D;

    // 1. degree -> dinv
    hipMemsetAsync(dinv, 0, N * sizeof(unsigned), stream);
    count_deg_kernel<<<(E + 255) / 256, 256, 0, stream>>>(dst, (unsigned*)dinv, E);
    dinv_kernel<<<(N + 255) / 256, 256, 0, stream>>>(dinv, N);

    const int gemm_grid = (N + TM - 1) / TM;        // 782
    const long n4 = (long)N * (D / 4);
    const int sl_grid = (int)((n4 + 255) / 256);
    const int es_grid = (E + 7) / 8;
    const int mean_grid = (N * 32 + 255) / 256;

    // 2. h1 = x @ W1
    gemm_kernel<<<gemm_grid, 256, 0, stream>>>(x, W1, bufA, nullptr, 0, N);
    // 3. agg1 = selfloop + scatter
    selfloop_init_kernel<<<sl_grid, 256, 0, stream>>>(bufA, dinv, bufB, N);
    edge_scatter_kernel<<<es_grid, 256, 0, stream>>>(src, dst, dinv, bufA, bufB, E);
    // 4. h2 = leakyrelu(agg1 + b1) @ W2
    gemm_kernel<<<gemm_grid, 256, 0, stream>>>(bufB, W2, bufA, b1, 1, N);
    // 5. agg2
    selfloop_init_kernel<<<sl_grid, 256, 0, stream>>>(bufA, dinv, bufB, N);
    edge_scatter_kernel<<<es_grid, 256, 0, stream>>>(src, dst, dinv, bufA, bufB, E);
    // 6. mean(+b2)
    mean_kernel<<<mean_grid, 256, 0, stream>>>(bufB, b2, out, N);
}

// Round 2
// 431.811 us; speedup vs baseline: 13.0018x; 13.0018x over previous
//
#include <hip/hip_runtime.h>
#include <hip/hip_bf16.h>

// GCN: 2x GCNConv(128->128) + LeakyReLU(0.1) + mean over channels.
// N=50000, E=1600000, D=128, fp32.
//
// R2 restructure (kills the 2x2677us atomic scatter):
//  - CSR build (deg histogram -> scan -> fill), gather-aggregate (no f32 atomics)
//  - GEMM1 epilogue pre-scales: g[u] = dinv[u] * (x@W1)[u]
//    => agg1[v] = dinv[v] * (g[v] + sum_{e->v} g[src_e])   (no per-edge weights)
//  - mean over channels is linear => second conv collapses to scalars:
//      w2m[k]  = mean_j W2[k,j],  meanb2 = mean(b2)
//      mg[u]   = dinv[u] * dot(leakyrelu(agg1[u] + b1), w2m)
//      out[v]  = dinv[v] * (mg[v] + sum_{e->v} mg[src_e]) + meanb2
//    agg1 never materialized; 2nd aggregation gathers 4B scalars from 200KB.

#define N_NODES 50000
#define D 128

// ---------------- degree histogram ----------------
__global__ void count_deg_kernel(const int* __restrict__ dst, unsigned* __restrict__ cnt, int E) {
    int e = blockIdx.x * blockDim.x + threadIdx.x;
    if (e < E) atomicAdd(&cnt[dst[e]], 1u);
}

__global__ void dinv_kernel(const unsigned* __restrict__ deg, float* __restrict__ dinv, int N) {
    int i = blockIdx.x * blockDim.x + threadIdx.x;
    if (i < N) dinv[i] = rsqrtf((float)(deg[i] + 1u));   // +1 self-loop
}

// ---------------- exclusive scan of deg -> row (3 kernels) ----------------
__global__ void scan_partial_kernel(const unsigned* __restrict__ deg, int* __restrict__ row,
                                    unsigned* __restrict__ bsum, int N) {
    __shared__ unsigned s[256];
    int t = threadIdx.x;
    int i = blockIdx.x * 256 + t;
    unsigned v = (i < N) ? deg[i] : 0u;
    s[t] = v;
    __syncthreads();
#pragma unroll
    for (int off = 1; off < 256; off <<= 1) {
        unsigned u = (t >= off) ? s[t - off] : 0u;
        __syncthreads();
        s[t] += u;
        __syncthreads();
    }
    if (i < N) row[i] = (int)(s[t] - v);       // exclusive
    if (t == 255) bsum[blockIdx.x] = s[255];
}

__global__ void scan_top_kernel(unsigned* __restrict__ bsum, int* __restrict__ row,
                                int nblocks, int N, int E) {
    __shared__ unsigned s[256];
    int t = threadIdx.x;
    unsigned v = (t < nblocks) ? bsum[t] : 0u;
    s[t] = v;
    __syncthreads();
#pragma unroll
    for (int off = 1; off < 256; off <<= 1) {
        unsigned u = (t >= off) ? s[t - off] : 0u;
        __syncthreads();
        s[t] += u;
        __syncthreads();
    }
    if (t < nblocks) bsum[t] = s[t] - v;       // exclusive block offsets
    if (t == 0) row[N] = E;
}

__global__ void scan_add_kernel(int* __restrict__ row, const unsigned* __restrict__ bsum, int N) {
    int i = blockIdx.x * 256 + threadIdx.x;
    if (i < N) row[i] += (int)bsum[blockIdx.x];
}

// ---------------- CSR fill ----------------
__global__ void fill_kernel(const int* __restrict__ src, const int* __restrict__ dst,
                            const int* __restrict__ row, unsigned* __restrict__ cursor,
                            int* __restrict__ esrc, int E) {
    int e = blockIdx.x * blockDim.x + threadIdx.x;
    if (e >= E) return;
    int d = dst[e];
    int slot = row[d] + (int)atomicAdd(&cursor[d], 1u);
    esrc[slot] = src[e];
}

// ---------------- w2m = mean_j W2[k,j]; w2m[128] = mean(b2) ----------------
__global__ void w2m_kernel(const float* __restrict__ W2, const float* __restrict__ b2,
                           float* __restrict__ w2m) {
    int k = threadIdx.x;   // 128 threads
    float s = 0.f;
    for (int j = 0; j < 128; j++) s += W2[k * 128 + j];
    w2m[k] = s * (1.0f / 128.0f);
    if (k == 0) {
        float t = 0.f;
        for (int j = 0; j < 128; j++) t += b2[j];
        w2m[128] = t * (1.0f / 128.0f);
    }
}

// ---------------- GEMM: g[M,128] = dinv[row] * (A @ W) ----------------
#define TM 64
__global__ __launch_bounds__(256) void gemm_kernel(
    const float* __restrict__ A, const float* __restrict__ W,
    float* __restrict__ C, const float* __restrict__ dinv, int M) {
    __shared__ float Ws[128 * 128];   // 64 KB
    __shared__ float As[TM * 128];    // 32 KB
    int t = threadIdx.x;
    int row0 = blockIdx.x * TM;

    {
        const float4* Wv = (const float4*)W;
        float4* Wsv = (float4*)Ws;
#pragma unroll
        for (int i = 0; i < 16; i++) Wsv[t + i * 256] = Wv[t + i * 256];
    }
    {
        float4* Asv = (float4*)As;
#pragma unroll
        for (int i = 0; i < (TM * 32) / 256; i++) {
            int f = t + i * 256;
            int r = f >> 5;
            int c4 = f & 31;
            int row = row0 + r;
            float4 v = make_float4(0.f, 0.f, 0.f, 0.f);
            if (row < M) v = ((const float4*)(A + (long)row * D))[c4];
            Asv[f] = v;
        }
    }
    __syncthreads();

    int tx = t & 31;
    int ty = t >> 5;
    float4 acc[8];
#pragma unroll
    for (int r = 0; r < 8; r++) acc[r] = make_float4(0.f, 0.f, 0.f, 0.f);

    const float4* Wsv = (const float4*)Ws;
    for (int k = 0; k < 128; k += 4) {
        float4 w0 = Wsv[(k + 0) * 32 + tx];
        float4 w1 = Wsv[(k + 1) * 32 + tx];
        float4 w2 = Wsv[(k + 2) * 32 + tx];
        float4 w3 = Wsv[(k + 3) * 32 + tx];
#pragma unroll
        for (int r = 0; r < 8; r++) {
            int row = ty * 8 + r;
            float4 a = *(const float4*)(As + row * 128 + k);
            acc[r].x += a.x * w0.x + a.y * w1.x + a.z * w2.x + a.w * w3.x;
            acc[r].y += a.x * w0.y + a.y * w1.y + a.z * w2.y + a.w * w3.y;
            acc[r].z += a.x * w0.z + a.y * w1.z + a.z * w2.z + a.w * w3.z;
            acc[r].w += a.x * w0.w + a.y * w1.w + a.z * w2.w + a.w * w3.w;
        }
    }
#pragma unroll
    for (int r = 0; r < 8; r++) {
        int row = row0 + ty * 8 + r;
        if (row < M) {
            float dv = dinv[row];
            float4 o = acc[r];
            o.x *= dv; o.y *= dv; o.z *= dv; o.w *= dv;
            ((float4*)(C + (long)row * D))[tx] = o;
        }
    }
}

// ---------------- fused gather + leakyrelu + dot(w2m): one 64-lane wave/node ----------------
__global__ __launch_bounds__(256) void gather_node_kernel(
    const int* __restrict__ row, const int* __restrict__ esrc,
    const float* __restrict__ g, const float* __restrict__ dinv,
    const float* __restrict__ b1, const float* __restrict__ w2m,
    float* __restrict__ mg, int N) {
    int wave = threadIdx.x >> 6;
    int lane = threadIdx.x & 63;
    int v = blockIdx.x * 4 + wave;
    if (v >= N) return;
    const float2* gv = (const float2*)g;
    float2 acc = gv[(long)v * 64 + lane];          // self-loop term g[v]
    int jb = row[v], je = row[v + 1];
    int j = jb;
    for (; j + 4 <= je; j += 4) {
        int s0 = esrc[j], s1 = esrc[j + 1], s2 = esrc[j + 2], s3 = esrc[j + 3];
        float2 a0 = gv[(long)s0 * 64 + lane];
        float2 a1 = gv[(long)s1 * 64 + lane];
        float2 a2 = gv[(long)s2 * 64 + lane];
        float2 a3 = gv[(long)s3 * 64 + lane];
        acc.x += a0.x + a1.x + a2.x + a3.x;
        acc.y += a0.y + a1.y + a2.y + a3.y;
    }
    for (; j < je; j++) {
        int s = esrc[j];
        float2 a = gv[(long)s * 64 + lane];
        acc.x += a.x; acc.y += a.y;
    }
    float dv = dinv[v];
    float2 bb = ((const float2*)b1)[lane];
    float tx = dv * acc.x + bb.x;
    float ty = dv * acc.y + bb.y;
    tx = tx >= 0.f ? tx : 0.1f * tx;
    ty = ty >= 0.f ? ty : 0.1f * ty;
    float2 wm = ((const float2*)w2m)[lane];
    float s = tx * wm.x + ty * wm.y;
#pragma unroll
    for (int off = 32; off > 0; off >>= 1) s += __shfl_down(s, off, 64);
    if (lane == 0) mg[v] = dv * s;
}

// ---------------- scalar aggregate for conv2 + mean ----------------
__global__ void out_kernel(const int* __restrict__ row, const int* __restrict__ esrc,
                           const float* __restrict__ mg, const float* __restrict__ dinv,
                           const float* __restrict__ w2m, float* __restrict__ out, int N) {
    int v = blockIdx.x * blockDim.x + threadIdx.x;
    if (v >= N) return;
    float acc = mg[v];
    int jb = row[v], je = row[v + 1];
    int j = jb;
    for (; j + 4 <= je; j += 4) {
        int s0 = esrc[j], s1 = esrc[j + 1], s2 = esrc[j + 2], s3 = esrc[j + 3];
        acc += mg[s0] + mg[s1] + mg[s2] + mg[s3];
    }
    for (; j < je; j++) acc += mg[esrc[j]];
    out[v] = dinv[v] * acc + w2m[128];
}

extern "C" void kernel_launch(void* const* d_in, const int* in_sizes, int n_in,
                              void* d_out, int out_size, void* d_ws, size_t ws_size,
                              hipStream_t stream) {
    const float* x  = (const float*)d_in[0];
    const int* ei   = (const int*)d_in[1];
    const float* W1 = (const float*)d_in[2];
    const float* b1 = (const float*)d_in[3];
    const float* W2 = (const float*)d_in[4];
    const float* b2 = (const float*)d_in[5];
    float* out = (float*)d_out;

    const int N = N_NODES;
    const int E = in_sizes[1] / 2;
    const int* src = ei;
    const int* dst = ei + E;
    const int nblocks = (N + 255) / 256;     // 196

    // workspace layout (4B units)
    unsigned* deg   = (unsigned*)d_ws;                    // [50048]
    float*    dinv  = (float*)(deg + 50048);              // [50048]
    int*      row   = (int*)(dinv + 50048);               // [50064] (N+1)
    unsigned* cursor= (unsigned*)(row + 50064);           // [50048]
    unsigned* bsum  = cursor + 50048;                     // [256]
    float*    w2m   = (float*)(bsum + 256);               // [256] ([128]=mean b2)
    float*    mg    = w2m + 256;                          // [50048]
    int*      esrc  = (int*)(mg + 50048);                 // [E]
    float*    g     = (float*)(esrc + E);                 // [N*D]

    hipMemsetAsync(deg, 0, N * sizeof(unsigned), stream);
    hipMemsetAsync(cursor, 0, N * sizeof(unsigned), stream);

    // degree + dinv
    count_deg_kernel<<<(E + 255) / 256, 256, 0, stream>>>(dst, deg, E);
    dinv_kernel<<<nblocks, 256, 0, stream>>>(deg, dinv, N);

    // CSR: scan + fill
    scan_partial_kernel<<<nblocks, 256, 0, stream>>>(deg, row, bsum, N);
    scan_top_kernel<<<1, 256, 0, stream>>>(bsum, row, nblocks, N, E);
    scan_add_kernel<<<nblocks, 256, 0, stream>>>(row, bsum, N);
    fill_kernel<<<(E + 255) / 256, 256, 0, stream>>>(src, dst, row, cursor, esrc, E);

    // w2m / mean(b2)
    w2m_kernel<<<1, 128, 0, stream>>>(W2, b2, w2m);

    // g = dinv * (x @ W1)
    gemm_kernel<<<(N + TM - 1) / TM, 256, 0, stream>>>(x, W1, g, dinv, N);

    // mg[v] = dinv[v] * dot(leakyrelu(dinv[v]*(g[v]+sum g[src]) + b1), w2m)
    gather_node_kernel<<<(N + 3) / 4, 256, 0, stream>>>(row, esrc, g, dinv, b1, w2m, mg, N);

    // out[v] = dinv[v] * (mg[v] + sum mg[src]) + mean(b2)
    out_kernel<<<nblocks, 256, 0, stream>>>(row, esrc, mg, dinv, w2m, out, N);
}

// Round 3
// 316.582 us; speedup vs baseline: 17.7341x; 1.3640x over previous
//
#include <hip/hip_runtime.h>
#include <hip/hip_bf16.h>

// GCN: 2x GCNConv(128->128) + LeakyReLU(0.1) + mean over channels.
// N=50000, E=1600000, D=128, fp32 in/out.
//
// R3: (a) CSR build: rank captured during degree histogram (u16), fill is
//     atomic-free; esrc stored as u16 (src<65536) -> 3.2MB, L2-resident
//     scatter (R2 showed 101MB WRITE_SIZE for 6.4MB esrc = 16x line thrash).
//     (b) g stored as packed bf16 (2 ch/uint) -> gather traffic halved
//     (R2 gather: 443MB TCC fetch, 121us, latency-bound at VALUBusy=17%).
//     Math (verified R2): g[u]=dinv[u]*(x@W1)[u];
//       mg[u]=dinv[u]*dot(lrelu(dinv[u]*(g[u]+sum g[nbr]) + b1), mean_j W2[:,j]);
//       out[v]=dinv[v]*(mg[v]+sum mg[nbr]) + mean(b2).

#define N_NODES 50000
#define D 128

typedef unsigned int uint;
typedef unsigned short u16;

__device__ __forceinline__ uint pack_bf2(float a, float b) {
    uint ua = __float_as_uint(a), ub = __float_as_uint(b);
    ua = (ua + 0x7fffu + ((ua >> 16) & 1u)) >> 16;   // RNE
    ub = (ub + 0x7fffu + ((ub >> 16) & 1u)) >> 16;
    return ua | (ub << 16);
}

// ---------------- degree histogram + per-edge rank ----------------
__global__ void count_rank_kernel(const int* __restrict__ dst, unsigned* __restrict__ deg,
                                  u16* __restrict__ rank, int E) {
    int e = blockIdx.x * blockDim.x + threadIdx.x;
    if (e < E) rank[e] = (u16)atomicAdd(&deg[dst[e]], 1u);   // in-deg max ~70 << 65536
}

__global__ void dinv_kernel(const unsigned* __restrict__ deg, float* __restrict__ dinv, int N) {
    int i = blockIdx.x * blockDim.x + threadIdx.x;
    if (i < N) dinv[i] = rsqrtf((float)(deg[i] + 1u));   // +1 self-loop
}

// ---------------- exclusive scan of deg -> row ----------------
__global__ void scan_partial_kernel(const unsigned* __restrict__ deg, int* __restrict__ row,
                                    unsigned* __restrict__ bsum, int N) {
    __shared__ unsigned s[256];
    int t = threadIdx.x;
    int i = blockIdx.x * 256 + t;
    unsigned v = (i < N) ? deg[i] : 0u;
    s[t] = v;
    __syncthreads();
#pragma unroll
    for (int off = 1; off < 256; off <<= 1) {
        unsigned u = (t >= off) ? s[t - off] : 0u;
        __syncthreads();
        s[t] += u;
        __syncthreads();
    }
    if (i < N) row[i] = (int)(s[t] - v);
    if (t == 255) bsum[blockIdx.x] = s[255];
}

__global__ void scan_top_kernel(unsigned* __restrict__ bsum, int* __restrict__ row,
                                int nblocks, int N, int E) {
    __shared__ unsigned s[256];
    int t = threadIdx.x;
    unsigned v = (t < nblocks) ? bsum[t] : 0u;
    s[t] = v;
    __syncthreads();
#pragma unroll
    for (int off = 1; off < 256; off <<= 1) {
        unsigned u = (t >= off) ? s[t - off] : 0u;
        __syncthreads();
        s[t] += u;
        __syncthreads();
    }
    if (t < nblocks) bsum[t] = s[t] - v;
    if (t == 0) row[N] = E;
}

__global__ void scan_add_kernel(int* __restrict__ row, const unsigned* __restrict__ bsum, int N) {
    int i = blockIdx.x * 256 + threadIdx.x;
    if (i < N) row[i] += (int)bsum[blockIdx.x];
}

// ---------------- CSR fill (atomic-free; rank precomputed) ----------------
__global__ void fill_kernel(const int* __restrict__ src, const int* __restrict__ dst,
                            const int* __restrict__ row, const u16* __restrict__ rank,
                            u16* __restrict__ esrc, int E) {
    int e = blockIdx.x * blockDim.x + threadIdx.x;
    if (e >= E) return;
    int d = dst[e];
    esrc[row[d] + (int)rank[e]] = (u16)src[e];
}

// ---------------- w2m = mean_j W2[k,j]; w2m[128] = mean(b2) ----------------
__global__ void w2m_kernel(const float* __restrict__ W2, const float* __restrict__ b2,
                           float* __restrict__ w2m) {
    int k = threadIdx.x;   // 128 threads
    float s = 0.f;
    for (int j = 0; j < 128; j++) s += W2[k * 128 + j];
    w2m[k] = s * (1.0f / 128.0f);
    if (k == 0) {
        float t = 0.f;
        for (int j = 0; j < 128; j++) t += b2[j];
        w2m[128] = t * (1.0f / 128.0f);
    }
}

// ---------------- GEMM: g16[M,64] = pack_bf16( dinv[row] * (A @ W) ) ----------------
#define TM 64
__global__ __launch_bounds__(256) void gemm_kernel(
    const float* __restrict__ A, const float* __restrict__ W,
    uint* __restrict__ G16, const float* __restrict__ dinv, int M) {
    __shared__ float Ws[128 * 128];   // 64 KB
    __shared__ float As[TM * 128];    // 32 KB
    int t = threadIdx.x;
    int row0 = blockIdx.x * TM;

    {
        const float4* Wv = (const float4*)W;
        float4* Wsv = (float4*)Ws;
#pragma unroll
        for (int i = 0; i < 16; i++) Wsv[t + i * 256] = Wv[t + i * 256];
    }
    {
        float4* Asv = (float4*)As;
#pragma unroll
        for (int i = 0; i < (TM * 32) / 256; i++) {
            int f = t + i * 256;
            int r = f >> 5;
            int c4 = f & 31;
            int row = row0 + r;
            float4 v = make_float4(0.f, 0.f, 0.f, 0.f);
            if (row < M) v = ((const float4*)(A + (long)row * D))[c4];
            Asv[f] = v;
        }
    }
    __syncthreads();

    int tx = t & 31;
    int ty = t >> 5;
    float4 acc[8];
#pragma unroll
    for (int r = 0; r < 8; r++) acc[r] = make_float4(0.f, 0.f, 0.f, 0.f);

    const float4* Wsv = (const float4*)Ws;
    for (int k = 0; k < 128; k += 4) {
        float4 w0 = Wsv[(k + 0) * 32 + tx];
        float4 w1 = Wsv[(k + 1) * 32 + tx];
        float4 w2 = Wsv[(k + 2) * 32 + tx];
        float4 w3 = Wsv[(k + 3) * 32 + tx];
#pragma unroll
        for (int r = 0; r < 8; r++) {
            int row = ty * 8 + r;
            float4 a = *(const float4*)(As + row * 128 + k);
            acc[r].x += a.x * w0.x + a.y * w1.x + a.z * w2.x + a.w * w3.x;
            acc[r].y += a.x * w0.y + a.y * w1.y + a.z * w2.y + a.w * w3.y;
            acc[r].z += a.x * w0.z + a.y * w1.z + a.z * w2.z + a.w * w3.z;
            acc[r].w += a.x * w0.w + a.y * w1.w + a.z * w2.w + a.w * w3.w;
        }
    }
#pragma unroll
    for (int r = 0; r < 8; r++) {
        int row = row0 + ty * 8 + r;
        if (row < M) {
            float dv = dinv[row];
            uint2 o;
            o.x = pack_bf2(acc[r].x * dv, acc[r].y * dv);
            o.y = pack_bf2(acc[r].z * dv, acc[r].w * dv);
            ((uint2*)G16)[(long)row * 32 + tx] = o;
        }
    }
}

// ---------------- fused gather(bf16) + leakyrelu + dot(w2m): one wave/node ----------------
__global__ __launch_bounds__(256) void gather_node_kernel(
    const int* __restrict__ row, const u16* __restrict__ esrc,
    const uint* __restrict__ g16, const float* __restrict__ dinv,
    const float* __restrict__ b1, const float* __restrict__ w2m,
    float* __restrict__ mg, int N) {
    int wave = threadIdx.x >> 6;
    int lane = threadIdx.x & 63;
    int v = blockIdx.x * 4 + wave;
    if (v >= N) return;

    uint u = g16[(long)v * 64 + lane];                 // self-loop term
    float ax = __uint_as_float(u << 16);
    float ay = __uint_as_float(u & 0xffff0000u);

    int jb = row[v], je = row[v + 1];
    int j = jb;
    for (; j + 8 <= je; j += 8) {
        int s0 = esrc[j + 0], s1 = esrc[j + 1], s2 = esrc[j + 2], s3 = esrc[j + 3];
        int s4 = esrc[j + 4], s5 = esrc[j + 5], s6 = esrc[j + 6], s7 = esrc[j + 7];
        uint u0 = g16[(long)s0 * 64 + lane];
        uint u1 = g16[(long)s1 * 64 + lane];
        uint u2 = g16[(long)s2 * 64 + lane];
        uint u3 = g16[(long)s3 * 64 + lane];
        uint u4 = g16[(long)s4 * 64 + lane];
        uint u5 = g16[(long)s5 * 64 + lane];
        uint u6 = g16[(long)s6 * 64 + lane];
        uint u7 = g16[(long)s7 * 64 + lane];
        ax += __uint_as_float(u0 << 16) + __uint_as_float(u1 << 16) +
              __uint_as_float(u2 << 16) + __uint_as_float(u3 << 16) +
              __uint_as_float(u4 << 16) + __uint_as_float(u5 << 16) +
              __uint_as_float(u6 << 16) + __uint_as_float(u7 << 16);
        ay += __uint_as_float(u0 & 0xffff0000u) + __uint_as_float(u1 & 0xffff0000u) +
              __uint_as_float(u2 & 0xffff0000u) + __uint_as_float(u3 & 0xffff0000u) +
              __uint_as_float(u4 & 0xffff0000u) + __uint_as_float(u5 & 0xffff0000u) +
              __uint_as_float(u6 & 0xffff0000u) + __uint_as_float(u7 & 0xffff0000u);
    }
    for (; j < je; j++) {
        uint uu = g16[(long)esrc[j] * 64 + lane];
        ax += __uint_as_float(uu << 16);
        ay += __uint_as_float(uu & 0xffff0000u);
    }
    float dv = dinv[v];
    float2 bb = ((const float2*)b1)[lane];
    float tx = dv * ax + bb.x;
    float ty = dv * ay + bb.y;
    tx = tx >= 0.f ? tx : 0.1f * tx;
    ty = ty >= 0.f ? ty : 0.1f * ty;
    float2 wm = ((const float2*)w2m)[lane];
    float s = tx * wm.x + ty * wm.y;
#pragma unroll
    for (int off = 32; off > 0; off >>= 1) s += __shfl_down(s, off, 64);
    if (lane == 0) mg[v] = dv * s;
}

// ---------------- scalar aggregate for conv2 + mean ----------------
__global__ void out_kernel(const int* __restrict__ row, const u16* __restrict__ esrc,
                           const float* __restrict__ mg, const float* __restrict__ dinv,
                           const float* __restrict__ w2m, float* __restrict__ out, int N) {
    int v = blockIdx.x * blockDim.x + threadIdx.x;
    if (v >= N) return;
    float acc = mg[v];
    int jb = row[v], je = row[v + 1];
    int j = jb;
    for (; j + 4 <= je; j += 4) {
        int s0 = esrc[j], s1 = esrc[j + 1], s2 = esrc[j + 2], s3 = esrc[j + 3];
        acc += mg[s0] + mg[s1] + mg[s2] + mg[s3];
    }
    for (; j < je; j++) acc += mg[esrc[j]];
    out[v] = dinv[v] * acc + w2m[128];
}

extern "C" void kernel_launch(void* const* d_in, const int* in_sizes, int n_in,
                              void* d_out, int out_size, void* d_ws, size_t ws_size,
                              hipStream_t stream) {
    const float* x  = (const float*)d_in[0];
    const int* ei   = (const int*)d_in[1];
    const float* W1 = (const float*)d_in[2];
    const float* b1 = (const float*)d_in[3];
    const float* W2 = (const float*)d_in[4];
    const float* b2 = (const float*)d_in[5];
    float* out = (float*)d_out;

    const int N = N_NODES;
    const int E = in_sizes[1] / 2;
    const int* src = ei;
    const int* dst = ei + E;
    const int nblocks = (N + 255) / 256;     // 196

    // workspace layout (4B units, then 2B arrays, then g16)
    unsigned* deg   = (unsigned*)d_ws;                    // [50048]
    float*    dinv  = (float*)(deg + 50048);              // [50048]
    int*      row   = (int*)(dinv + 50048);               // [50064] (N+1)
    unsigned* bsum  = (unsigned*)(row + 50064);           // [256]
    float*    w2m   = (float*)(bsum + 256);               // [256] ([128]=mean b2)
    float*    mg    = w2m + 256;                          // [50048]
    u16*      rank  = (u16*)(mg + 50048);                 // [E]
    u16*      esrc  = rank + E;                           // [E]
    uint*     g16   = (uint*)(esrc + E);                  // [N*64] packed bf16 pairs

    hipMemsetAsync(deg, 0, N * sizeof(unsigned), stream);

    // degree + per-edge rank, dinv
    count_rank_kernel<<<(E + 255) / 256, 256, 0, stream>>>(dst, deg, rank, E);
    dinv_kernel<<<nblocks, 256, 0, stream>>>(deg, dinv, N);

    // CSR: scan + atomic-free fill
    scan_partial_kernel<<<nblocks, 256, 0, stream>>>(deg, row, bsum, N);
    scan_top_kernel<<<1, 256, 0, stream>>>(bsum, row, nblocks, N, E);
    scan_add_kernel<<<nblocks, 256, 0, stream>>>(row, bsum, N);
    fill_kernel<<<(E + 255) / 256, 256, 0, stream>>>(src, dst, row, rank, esrc, E);

    // w2m / mean(b2)
    w2m_kernel<<<1, 128, 0, stream>>>(W2, b2, w2m);

    // g16 = bf16( dinv * (x @ W1) )
    gemm_kernel<<<(N + TM - 1) / TM, 256, 0, stream>>>(x, W1, g16, dinv, N);

    // mg[v] = dinv[v] * dot(leakyrelu(dinv[v]*(g[v]+sum g[nbr]) + b1), w2m)
    gather_node_kernel<<<(N + 3) / 4, 256, 0, stream>>>(row, esrc, g16, dinv, b1, w2m, mg, N);

    // out[v] = dinv[v] * (mg[v] + sum mg[nbr]) + mean(b2)
    out_kernel<<<nblocks, 256, 0, stream>>>(row, esrc, mg, dinv, w2m, out, N);
}

// Round 4
// 294.395 us; speedup vs baseline: 19.0706x; 1.0754x over previous
//
#include <hip/hip_runtime.h>
#include <hip/hip_bf16.h>

// GCN: 2x GCNConv(128->128) + LeakyReLU(0.1) + mean over channels.
// N=50000, E=1600000, D=128, fp32 in/out.
//
// R4: (a) XCD-partitioned degree histogram (8 private copies, block&7) to
//     kill cross-XCD atomic line ping-pong (R3: 53MB WRITE_SIZE, 71us).
//     (b) GEMM stages W in two 32KB K-slices -> LDS 64KB -> 2 blocks/CU
//     (R3: 96KB -> 1 wave/SIMD, occupancy 8.3%, 71us).
//     (c) gather uses uint4/lane (16 lanes/row, 4 neighbors in flight).
// Math (verified R2/R3): g[u]=dinv[u]*(x@W1)[u]  (stored bf16-packed);
//   mg[u]=dinv[u]*dot(lrelu(dinv[u]*(g[u]+sum g[nbr]) + b1), mean_j W2[:,j]);
//   out[v]=dinv[v]*(mg[v]+sum mg[nbr]) + mean(b2).

#define N_NODES 50000
#define NPAD 50048
#define D 128

typedef unsigned int uint;
typedef unsigned short u16;

__device__ __forceinline__ uint pack_bf2(float a, float b) {
    uint ua = __float_as_uint(a), ub = __float_as_uint(b);
    ua = (ua + 0x7fffu + ((ua >> 16) & 1u)) >> 16;   // RNE
    ub = (ub + 0x7fffu + ((ub >> 16) & 1u)) >> 16;
    return ua | (ub << 16);
}

// ---------------- partitioned degree histogram + per-edge local rank ----------------
__global__ void count_rank_kernel(const int* __restrict__ dst, uint* __restrict__ cnt,
                                  u16* __restrict__ rank, int E) {
    int e = blockIdx.x * blockDim.x + threadIdx.x;
    if (e >= E) return;
    int part = blockIdx.x & 7;                 // same partition recomputed in fill
    rank[e] = (u16)atomicAdd(&cnt[part * NPAD + dst[e]], 1u);
}

// deg/dinv/per-partition prefix from the 8 histograms
__global__ void combine_kernel(const uint* __restrict__ cnt, unsigned* __restrict__ deg,
                               float* __restrict__ dinv, u16* __restrict__ xoff, int N) {
    int i = blockIdx.x * 256 + threadIdx.x;
    if (i >= N) return;
    unsigned run = 0;
#pragma unroll
    for (int x = 0; x < 8; x++) {
        xoff[x * NPAD + i] = (u16)run;
        run += cnt[x * NPAD + i];
    }
    deg[i] = run;
    dinv[i] = rsqrtf((float)(run + 1u));       // +1 self-loop
}

// ---------------- exclusive scan of deg -> row ----------------
__global__ void scan_partial_kernel(const unsigned* __restrict__ deg, int* __restrict__ row,
                                    unsigned* __restrict__ bsum, int N) {
    __shared__ unsigned s[256];
    int t = threadIdx.x;
    int i = blockIdx.x * 256 + t;
    unsigned v = (i < N) ? deg[i] : 0u;
    s[t] = v;
    __syncthreads();
#pragma unroll
    for (int off = 1; off < 256; off <<= 1) {
        unsigned u = (t >= off) ? s[t - off] : 0u;
        __syncthreads();
        s[t] += u;
        __syncthreads();
    }
    if (i < N) row[i] = (int)(s[t] - v);
    if (t == 255) bsum[blockIdx.x] = s[255];
}

__global__ void scan_top_kernel(unsigned* __restrict__ bsum, int* __restrict__ row,
                                int nblocks, int N, int E) {
    __shared__ unsigned s[256];
    int t = threadIdx.x;
    unsigned v = (t < nblocks) ? bsum[t] : 0u;
    s[t] = v;
    __syncthreads();
#pragma unroll
    for (int off = 1; off < 256; off <<= 1) {
        unsigned u = (t >= off) ? s[t - off] : 0u;
        __syncthreads();
        s[t] += u;
        __syncthreads();
    }
    if (t < nblocks) bsum[t] = s[t] - v;
    if (t == 0) row[N] = E;
}

__global__ void scan_add_kernel(int* __restrict__ row, const unsigned* __restrict__ bsum, int N) {
    int i = blockIdx.x * 256 + threadIdx.x;
    if (i < N) row[i] += (int)bsum[blockIdx.x];
}

// ---------------- CSR fill (atomic-free) ----------------
__global__ void fill_kernel(const int* __restrict__ src, const int* __restrict__ dst,
                            const int* __restrict__ row, const u16* __restrict__ rank,
                            const u16* __restrict__ xoff, u16* __restrict__ esrc, int E) {
    int e = blockIdx.x * blockDim.x + threadIdx.x;
    if (e >= E) return;
    int part = blockIdx.x & 7;
    int d = dst[e];
    esrc[row[d] + (int)xoff[part * NPAD + d] + (int)rank[e]] = (u16)src[e];
}

// ---------------- w2m = mean_j W2[k,j]; w2m[128] = mean(b2) ----------------
__global__ void w2m_kernel(const float* __restrict__ W2, const float* __restrict__ b2,
                           float* __restrict__ w2m) {
    int k = threadIdx.x;   // 128 threads
    float s = 0.f;
    for (int j = 0; j < 128; j++) s += W2[k * 128 + j];
    w2m[k] = s * (1.0f / 128.0f);
    if (k == 0) {
        float t = 0.f;
        for (int j = 0; j < 128; j++) t += b2[j];
        w2m[128] = t * (1.0f / 128.0f);
    }
}

// ---------------- GEMM: g16[M,64] = pack_bf16( dinv[row] * (A @ W) ) ----------------
// Two-phase K staging: Ws holds a 64-row K-slice (32KB); LDS total 64KB -> 2 blocks/CU.
#define TM 64
__global__ __launch_bounds__(256) void gemm_kernel(
    const float* __restrict__ A, const float* __restrict__ W,
    uint* __restrict__ G16, const float* __restrict__ dinv, int M) {
    __shared__ float Ws[64 * 128];    // 32 KB (K-slice)
    __shared__ float As[TM * 128];    // 32 KB
    int t = threadIdx.x;
    int row0 = blockIdx.x * TM;

    {   // stage A tile (full K)
        float4* Asv = (float4*)As;
#pragma unroll
        for (int i = 0; i < (TM * 32) / 256; i++) {
            int f = t + i * 256;
            int r = f >> 5;
            int c4 = f & 31;
            int row = row0 + r;
            float4 v = make_float4(0.f, 0.f, 0.f, 0.f);
            if (row < M) v = ((const float4*)(A + (long)row * D))[c4];
            Asv[f] = v;
        }
    }

    int tx = t & 31;
    int ty = t >> 5;
    float4 acc[8];
#pragma unroll
    for (int r = 0; r < 8; r++) acc[r] = make_float4(0.f, 0.f, 0.f, 0.f);

    const float4* Wsv = (const float4*)Ws;
    for (int ph = 0; ph < 2; ph++) {
        __syncthreads();   // ph0: A-stage barrier; ph1: protect Ws from prev readers
        {   // stage W K-slice: rows ph*64 .. ph*64+63
            const float4* Wv = (const float4*)(W + ph * 64 * 128);
            float4* Wsv_w = (float4*)Ws;
#pragma unroll
            for (int i = 0; i < 8; i++) Wsv_w[t + i * 256] = Wv[t + i * 256];
        }
        __syncthreads();
        for (int k = 0; k < 64; k += 4) {
            float4 w0 = Wsv[(k + 0) * 32 + tx];
            float4 w1 = Wsv[(k + 1) * 32 + tx];
            float4 w2 = Wsv[(k + 2) * 32 + tx];
            float4 w3 = Wsv[(k + 3) * 32 + tx];
#pragma unroll
            for (int r = 0; r < 8; r++) {
                int row = ty * 8 + r;
                float4 a = *(const float4*)(As + row * 128 + ph * 64 + k);
                acc[r].x += a.x * w0.x + a.y * w1.x + a.z * w2.x + a.w * w3.x;
                acc[r].y += a.x * w0.y + a.y * w1.y + a.z * w2.y + a.w * w3.y;
                acc[r].z += a.x * w0.z + a.y * w1.z + a.z * w2.z + a.w * w3.z;
                acc[r].w += a.x * w0.w + a.y * w1.w + a.z * w2.w + a.w * w3.w;
            }
        }
    }
#pragma unroll
    for (int r = 0; r < 8; r++) {
        int row = row0 + ty * 8 + r;
        if (row < M) {
            float dv = dinv[row];
            uint2 o;
            o.x = pack_bf2(acc[r].x * dv, acc[r].y * dv);
            o.y = pack_bf2(acc[r].z * dv, acc[r].w * dv);
            ((uint2*)G16)[(long)row * 32 + tx] = o;
        }
    }
}

// ---------------- fused gather(bf16) + leakyrelu + dot(w2m) ----------------
// One wave/node; 16 lanes (uint4 each) cover the 256B row; 4 neighbors in flight.
__global__ __launch_bounds__(256) void gather_node_kernel(
    const int* __restrict__ row, const u16* __restrict__ esrc,
    const uint* __restrict__ g16, const float* __restrict__ dinv,
    const float* __restrict__ b1, const float* __restrict__ w2m,
    float* __restrict__ mg, int N) {
    int wave = threadIdx.x >> 6;
    int lane = threadIdx.x & 63;
    int sub = lane & 15;       // uint4 slot within row
    int grp = lane >> 4;       // neighbor slot (4 concurrent)
    int v = blockIdx.x * 4 + wave;
    if (v >= N) return;

    const uint4* gv = (const uint4*)g16;   // row stride = 16 uint4
    float a0 = 0.f, a1 = 0.f, a2 = 0.f, a3 = 0.f, a4 = 0.f, a5 = 0.f, a6 = 0.f, a7 = 0.f;

#define ACCUM(u)                                                        \
    a0 += __uint_as_float((u).x << 16); a1 += __uint_as_float((u).x & 0xffff0000u); \
    a2 += __uint_as_float((u).y << 16); a3 += __uint_as_float((u).y & 0xffff0000u); \
    a4 += __uint_as_float((u).z << 16); a5 += __uint_as_float((u).z & 0xffff0000u); \
    a6 += __uint_as_float((u).w << 16); a7 += __uint_as_float((u).w & 0xffff0000u);

    if (grp == 0) {            // self-loop term
        uint4 u = gv[(long)v * 16 + sub];
        ACCUM(u)
    }
    int jb = row[v], je = row[v + 1];
    int j = jb + grp;
    for (; j + 4 < je; j += 8) {
        int s0 = esrc[j], s1 = esrc[j + 4];
        uint4 u0 = gv[(long)s0 * 16 + sub];
        uint4 u1 = gv[(long)s1 * 16 + sub];
        ACCUM(u0)
        ACCUM(u1)
    }
    for (; j < je; j += 4) {
        int s = esrc[j];
        uint4 u = gv[(long)s * 16 + sub];
        ACCUM(u)
    }
#undef ACCUM

    // reduce the 4 neighbor groups
#define RED(a) a += __shfl_xor(a, 16, 64); a += __shfl_xor(a, 32, 64);
    RED(a0) RED(a1) RED(a2) RED(a3) RED(a4) RED(a5) RED(a6) RED(a7)
#undef RED

    if (grp == 0) {            // lanes 0..15 hold channels 8*sub .. 8*sub+7
        float dv = dinv[v];
        const float2* bp = (const float2*)b1;
        const float2* wp = (const float2*)w2m;
        float s = 0.f;
        float2 bb, wm;
        bb = bp[4 * sub + 0]; wm = wp[4 * sub + 0];
        float t0 = dv * a0 + bb.x; t0 = t0 >= 0.f ? t0 : 0.1f * t0;
        float t1 = dv * a1 + bb.y; t1 = t1 >= 0.f ? t1 : 0.1f * t1;
        s += t0 * wm.x + t1 * wm.y;
        bb = bp[4 * sub + 1]; wm = wp[4 * sub + 1];
        t0 = dv * a2 + bb.x; t0 = t0 >= 0.f ? t0 : 0.1f * t0;
        t1 = dv * a3 + bb.y; t1 = t1 >= 0.f ? t1 : 0.1f * t1;
        s += t0 * wm.x + t1 * wm.y;
        bb = bp[4 * sub + 2]; wm = wp[4 * sub + 2];
        t0 = dv * a4 + bb.x; t0 = t0 >= 0.f ? t0 : 0.1f * t0;
        t1 = dv * a5 + bb.y; t1 = t1 >= 0.f ? t1 : 0.1f * t1;
        s += t0 * wm.x + t1 * wm.y;
        bb = bp[4 * sub + 3]; wm = wp[4 * sub + 3];
        t0 = dv * a6 + bb.x; t0 = t0 >= 0.f ? t0 : 0.1f * t0;
        t1 = dv * a7 + bb.y; t1 = t1 >= 0.f ? t1 : 0.1f * t1;
        s += t0 * wm.x + t1 * wm.y;
        s += __shfl_xor(s, 1, 64);
        s += __shfl_xor(s, 2, 64);
        s += __shfl_xor(s, 4, 64);
        s += __shfl_xor(s, 8, 64);
        if (sub == 0) mg[v] = dv * s;
    }
}

// ---------------- scalar aggregate for conv2 + mean ----------------
__global__ void out_kernel(const int* __restrict__ row, const u16* __restrict__ esrc,
                           const float* __restrict__ mg, const float* __restrict__ dinv,
                           const float* __restrict__ w2m, float* __restrict__ out, int N) {
    int v = blockIdx.x * blockDim.x + threadIdx.x;
    if (v >= N) return;
    float acc = mg[v];
    int jb = row[v], je = row[v + 1];
    int j = jb;
    for (; j + 8 <= je; j += 8) {
        acc += mg[esrc[j]] + mg[esrc[j + 1]] + mg[esrc[j + 2]] + mg[esrc[j + 3]] +
               mg[esrc[j + 4]] + mg[esrc[j + 5]] + mg[esrc[j + 6]] + mg[esrc[j + 7]];
    }
    for (; j < je; j++) acc += mg[esrc[j]];
    out[v] = dinv[v] * acc + w2m[128];
}

extern "C" void kernel_launch(void* const* d_in, const int* in_sizes, int n_in,
                              void* d_out, int out_size, void* d_ws, size_t ws_size,
                              hipStream_t stream) {
    const float* x  = (const float*)d_in[0];
    const int* ei   = (const int*)d_in[1];
    const float* W1 = (const float*)d_in[2];
    const float* b1 = (const float*)d_in[3];
    const float* W2 = (const float*)d_in[4];
    const float* b2 = (const float*)d_in[5];
    float* out = (float*)d_out;

    const int N = N_NODES;
    const int E = in_sizes[1] / 2;
    const int* src = ei;
    const int* dst = ei + E;
    const int nblocks = (N + 255) / 256;     // 196

    // workspace layout (4B units). rank & cnt alias g16 (dead before gemm writes it).
    unsigned* deg   = (unsigned*)d_ws;                    // [NPAD]
    float*    dinv  = (float*)(deg + NPAD);               // [NPAD]
    int*      row   = (int*)(dinv + NPAD);                // [N+1 -> NPAD+16]
    unsigned* bsum  = (unsigned*)(row + NPAD + 16);       // [256]
    float*    w2m   = (float*)(bsum + 256);               // [256] ([128]=mean b2)
    float*    mg    = w2m + 256;                          // [NPAD]
    u16*      xoff  = (u16*)(mg + NPAD);                  // [8*NPAD] u16
    u16*      esrc  = xoff + 8 * NPAD;                    // [E] u16
    uint*     g16   = (uint*)(esrc + E + (E & 1));        // [N*32 uint2 = N*64 uint]
    u16*      rank  = (u16*)g16;                          // [E] u16   (alias, dead after fill)
    uint*     cnt   = g16 + E / 2;                        // [8*NPAD]  (alias, dead after combine)

    hipMemsetAsync(cnt, 0, 8 * NPAD * sizeof(uint), stream);

    // partitioned histogram + local rank
    count_rank_kernel<<<(E + 255) / 256, 256, 0, stream>>>(dst, cnt, rank, E);
    combine_kernel<<<nblocks, 256, 0, stream>>>(cnt, deg, dinv, xoff, N);

    // CSR: scan + atomic-free fill
    scan_partial_kernel<<<nblocks, 256, 0, stream>>>(deg, row, bsum, N);
    scan_top_kernel<<<1, 256, 0, stream>>>(bsum, row, nblocks, N, E);
    scan_add_kernel<<<nblocks, 256, 0, stream>>>(row, bsum, N);
    fill_kernel<<<(E + 255) / 256, 256, 0, stream>>>(src, dst, row, rank, xoff, esrc, E);

    // w2m / mean(b2)
    w2m_kernel<<<1, 128, 0, stream>>>(W2, b2, w2m);

    // g16 = bf16( dinv * (x @ W1) )   (clobbers rank/cnt aliases)
    gemm_kernel<<<(N + TM - 1) / TM, 256, 0, stream>>>(x, W1, g16, dinv, N);

    // mg[v] = dinv[v] * dot(leakyrelu(dinv[v]*(g[v]+sum g[nbr]) + b1), w2m)
    gather_node_kernel<<<(N + 3) / 4, 256, 0, stream>>>(row, esrc, g16, dinv, b1, w2m, mg, N);

    // out[v] = dinv[v] * (mg[v] + sum mg[nbr]) + mean(b2)
    out_kernel<<<nblocks, 256, 0, stream>>>(row, esrc, mg, dinv, w2m, out, N);
}